// Round 1
// baseline (432.068 us; speedup 1.0000x reference)
//
#include <hip/hip_runtime.h>

typedef unsigned short ush;
typedef unsigned int uint32;
typedef __attribute__((ext_vector_type(8))) __bf16 bf16x8;
typedef __attribute__((ext_vector_type(4))) float f32x4;

#define NBLK 256
#define RB   4     // batch rows per block
#define NTHR 512
#define SENC 256
#define TDEC 512
#define HDIM 128
#define HSTR 144   // h row stride (ush): 72 dw ≡ 8 mod 32 -> replicated reads/writes 2-way (free)
#define XSTR 520   // x row stride (ush)
#define PSTR 1024  // pred row stride (ush)

#define LOG2E  1.4426950408889634f
#define LOG2E2 2.8853900817779268f

__device__ __forceinline__ float bf2f(ush u){
  uint32 v = ((uint32)u) << 16;
  return __builtin_bit_cast(float, v);
}
__device__ __forceinline__ ush f2bf(float f){            // RNE via v_cvt
  return __builtin_bit_cast(ush, (__bf16)f);
}
__device__ __forceinline__ float lo16f(uint32 w){ return __builtin_bit_cast(float, w << 16); }
__device__ __forceinline__ float hi16f(uint32 w){ return __builtin_bit_cast(float, w & 0xFFFF0000u); }

__device__ __forceinline__ float loadf(const void* p, int i, bool f32){
  return f32 ? ((const float*)p)[i] : bf2f(((const ush*)p)[i]);
}
// raw bf16 fragment load: bit-exact copy of harness weights for bf16 inputs
__device__ __forceinline__ bf16x8 load8bf(const void* p, int i, bool f32){
  bf16x8 r;
  if (!f32){
    uint4 u = *reinterpret_cast<const uint4*>((const ush*)p + i);
    r = __builtin_bit_cast(bf16x8, u);
  } else {
    const float* fp = (const float*)p + i;
    #pragma unroll
    for (int j = 0; j < 8; ++j) r[j] = (__bf16)fp[j];
  }
  return r;
}
__device__ __forceinline__ float sigm(float x){
  return __builtin_amdgcn_rcpf(1.0f + __builtin_amdgcn_exp2f(-x * LOG2E));
}
__device__ __forceinline__ float tnh(float x){
  return 1.0f - 2.0f * __builtin_amdgcn_rcpf(__builtin_amdgcn_exp2f(x * LOG2E2) + 1.0f);
}
__device__ __forceinline__ f32x4 M1(bf16x8 a, bf16x8 b, f32x4 c){
  return __builtin_amdgcn_mfma_f32_16x16x32_bf16(a, b, c, 0, 0, 0);
}

// 256 blocks x 4 batch rows, 8 waves/block; wave w owns hidden cols [16w,16w+16).
// A-ROW REPLICATION: A[m] = h[m>>2] -> C[4q+r][n] = gates[q][n] in every reg;
// lane (n,q) reads acc[0] directly. Gate K=128 split into TWO independent
// depth-2 chains (A: kk0/1 with bias as C; B: kk2/3 with zero C), ALL issued
// before any acc[0] use -> acc wait is ~2 MFMA latencies, not ~8.
// DECODER WEIGHT FOLDING: pred feedback pred_d = h*Wfc+bfc enters the next
// cell as Wih*pred_d, and both are functions of the SAME h, so
//   Whh' = Whh + Wih[:,0]x Wfc[0] + Wih[:,1]x Wfc[1],  bias' = bias + Wih*bfc
// makes the decoder a pure h-recurrence: no pred chain, no shfl_xor, no
// feedback FMAs on the critical path. Wave 0 computes pred as an independent
// depth-2 chain purely for the output store. One barrier/step.
__global__ void __launch_bounds__(NTHR, 2)
lstm_kernel(const void* __restrict__ xg,  const void* __restrict__ wih,
            const void* __restrict__ whh, const void* __restrict__ bih,
            const void* __restrict__ bhh, const void* __restrict__ wfc,
            const void* __restrict__ bfc, void* __restrict__ outg)
{
  __shared__ __attribute__((aligned(16))) ush x_lds[RB * XSTR];      // [row][t*2+c]
  __shared__ __attribute__((aligned(16))) ush h_lds[2][RB * HSTR];   // [buf][row][j]
  __shared__ __attribute__((aligned(16))) ush pred_lds[RB][PSTR];    // [row][d*2+o]

  const int tid   = threadIdx.x;
  const int lane  = tid & 63;
  const int wv    = tid >> 6;
  const int n     = lane & 15;   // MFMA col index within tile (= A-row m)
  const int q     = lane >> 4;   // quad; this lane's batch row
  const int gbase = wv << 4;
  const int blk   = blockIdx.x;

  // runtime storage-dtype detection (bf16 vs f32) from w_hh bit patterns
  const uint32* wp = (const uint32*)whh;
  int cnt = 0;
  #pragma unroll
  for (int i = 0; i < 64; ++i){
    uint32 e = (wp[i] >> 7) & 0xFFu;
    cnt += (e >= 90u && e <= 140u) ? 1 : 0;
  }
  const bool isf32 = (cnt < 40);

  for (int i = tid; i < 2 * RB * HSTR; i += NTHR) h_lds[0][i] = 0;  // both bufs

  // stage this block's 4 encoder rows into LDS as bf16: [row][t*2+c]
  if (!isf32){
    if (tid < 256){
      int row = tid >> 6, c = (tid & 63) * 8;
      uint4 v = *reinterpret_cast<const uint4*>((const ush*)xg + (blk * RB + row) * (SENC * 2) + c);
      *reinterpret_cast<uint4*>(&x_lds[row * XSTR + c]) = v;
    }
  } else {
    for (int i = tid; i < RB * SENC * 2; i += NTHR){
      int row = i >> 9, c = i & 511;
      x_lds[row * XSTR + c] = f2bf(((const float*)xg)[(blk * RB + row) * (SENC * 2) + c]);
    }
  }

  // ---- loop-invariant preloads: weights RAW (bit-exact for bf16) ----
  float wih0v[4], wih1v[4];
  f32x4 biasC[4];    // broadcast bias, used as C operand of first MFMA (chain A)
  bf16x8 bfr[4][4];  // [gate p][kk]: B[k][g]=Whh[g][k], k=kk*32+q*8+j, g=p*128+gbase+n
  #pragma unroll
  for (int p = 0; p < 4; ++p){
    int g = p * 128 + gbase + n;
    float b = loadf(bih, g, isf32) + loadf(bhh, g, isf32);
    biasC[p][0] = b; biasC[p][1] = b; biasC[p][2] = b; biasC[p][3] = b;
    wih0v[p] = loadf(wih, g * 2 + 0, isf32);
    wih1v[p] = loadf(wih, g * 2 + 1, isf32);
    #pragma unroll
    for (int kk = 0; kk < 4; ++kk)
      bfr[p][kk] = load8bf(whh, g * HDIM + kk * 32 + q * 8, isf32);
  }
  // pred tile B-frag, COLUMN-REPLICATED: B[k][n] = wfc[n&1][k]
  bf16x8 wfcfr[4];
  #pragma unroll
  for (int kk = 0; kk < 4; ++kk){
    #pragma unroll
    for (int j = 0; j < 8; ++j){
      int k = kk * 32 + q * 8 + j;
      wfcfr[kk][j] = (__bf16)loadf(wfc, (n & 1) * HDIM + k, isf32);
    }
  }
  f32x4 pbfcC;
  {
    float pb = loadf(bfc, n & 1, isf32);
    pbfcC[0] = pb; pbfcC[1] = pb; pbfcC[2] = pb; pbfcC[3] = pb;
  }

  float cc = 0.0f;                   // c-state for (row q, col gbase+n)
  const int arow  = (n >> 2) * HSTR; // replicated A-row base: A[m]=h[m>>2]
  const int hwofs = q * HSTR + gbase + n;  // this lane's h-write offset
  int cur = 0;
  const f32x4 Z = {0.0f, 0.0f, 0.0f, 0.0f};

  __syncthreads();

  // ---------------- encoder (+ first decode cell at s==SENC) ----------------
  #pragma unroll 1
  for (int s = 0; s <= SENC; ++s){
    int t = (s < SENC) ? s : SENC - 1;   // s==SENC: inp0 = x[:,-1,:]
    uint32 xw = *reinterpret_cast<const uint32*>(&x_lds[q * XSTR + t * 2]);

    const ush* hb = &h_lds[cur][arow];
    bf16x8 af0 = *reinterpret_cast<const bf16x8*>(hb + 0 * 32 + q * 8);
    bf16x8 af1 = *reinterpret_cast<const bf16x8*>(hb + 1 * 32 + q * 8);
    bf16x8 af2 = *reinterpret_cast<const bf16x8*>(hb + 2 * 32 + q * 8);
    bf16x8 af3 = *reinterpret_cast<const bf16x8*>(hb + 3 * 32 + q * 8);

    // stage 1: 8 independent MFMAs
    f32x4 A0 = M1(af0, bfr[0][0], biasC[0]);
    f32x4 A1 = M1(af0, bfr[1][0], biasC[1]);
    f32x4 A2 = M1(af0, bfr[2][0], biasC[2]);
    f32x4 A3 = M1(af0, bfr[3][0], biasC[3]);
    f32x4 B0 = M1(af2, bfr[0][2], Z);
    f32x4 B1 = M1(af2, bfr[1][2], Z);
    f32x4 B2 = M1(af2, bfr[2][2], Z);
    f32x4 B3 = M1(af2, bfr[3][2], Z);
    // stage 2
    A0 = M1(af1, bfr[0][1], A0);
    A1 = M1(af1, bfr[1][1], A1);
    A2 = M1(af1, bfr[2][1], A2);
    A3 = M1(af1, bfr[3][1], A3);
    B0 = M1(af3, bfr[0][3], B0);
    B1 = M1(af3, bfr[1][3], B1);
    B2 = M1(af3, bfr[2][3], B2);
    B3 = M1(af3, bfr[3][3], B3);

    // x contribution computed in MFMA shadow (independent of accs)
    float xa = lo16f(xw), xb = hi16f(xw);
    float xc0 = wih0v[0] * xa + wih1v[0] * xb;
    float xc1 = wih0v[1] * xa + wih1v[1] * xb;
    float xc2 = wih0v[2] * xa + wih1v[2] * xb;
    float xc3 = wih0v[3] * xa + wih1v[3] * xb;

    float g0 = A0[0] + B0[0] + xc0;
    float g1 = A1[0] + B1[0] + xc1;
    float g2 = A2[0] + B2[0] + xc2;
    float g3 = A3[0] + B3[0] + xc3;
    float si = sigm(g0);
    float sf = sigm(g1);
    float tg = tnh(g2);
    float so = sigm(g3);
    cc = sf * cc + si * tg;
    h_lds[cur ^ 1][hwofs] = f2bf(so * tnh(cc));

    __syncthreads();
    cur ^= 1;
  }

  // ---- decoder weight folding (once, in-register): ----
  //   Whh'[g][k] = Whh[g][k] + wih0[g]*wfc[0][k] + wih1[g]*wfc[1][k]
  //   bias'[g]   = bias[g]   + wih0[g]*bfc[0]    + wih1[g]*bfc[1]
  {
    float bfc0 = loadf(bfc, 0, isf32), bfc1 = loadf(bfc, 1, isf32);
    #pragma unroll
    for (int p = 0; p < 4; ++p){
      float nb = biasC[p][0] + wih0v[p] * bfc0 + wih1v[p] * bfc1;
      biasC[p][0] = nb; biasC[p][1] = nb; biasC[p][2] = nb; biasC[p][3] = nb;
    }
    #pragma unroll
    for (int kk = 0; kk < 4; ++kk){
      #pragma unroll
      for (int j = 0; j < 8; ++j){
        int k = kk * 32 + q * 8 + j;
        float w0 = loadf(wfc, k, isf32);          // wfc[0][k]
        float w1 = loadf(wfc, HDIM + k, isf32);   // wfc[1][k]
        #pragma unroll
        for (int p = 0; p < 4; ++p)
          bfr[p][kk][j] = (__bf16)((float)bfr[p][kk][j] + wih0v[p] * w0 + wih1v[p] * w1);
      }
    }
  }

  // ---------------- decoder: pure h-recurrence (folded weights) -------------
  #pragma unroll 1
  for (int d = 0; d < TDEC - 1; ++d){
    const ush* hb = &h_lds[cur][arow];
    bf16x8 af0 = *reinterpret_cast<const bf16x8*>(hb + 0 * 32 + q * 8);
    bf16x8 af1 = *reinterpret_cast<const bf16x8*>(hb + 1 * 32 + q * 8);
    bf16x8 af2 = *reinterpret_cast<const bf16x8*>(hb + 2 * 32 + q * 8);
    bf16x8 af3 = *reinterpret_cast<const bf16x8*>(hb + 3 * 32 + q * 8);

    // stage 1: 8 independent gate MFMAs
    f32x4 A0 = M1(af0, bfr[0][0], biasC[0]);
    f32x4 A1 = M1(af0, bfr[1][0], biasC[1]);
    f32x4 A2 = M1(af0, bfr[2][0], biasC[2]);
    f32x4 A3 = M1(af0, bfr[3][0], biasC[3]);
    f32x4 B0 = M1(af2, bfr[0][2], Z);
    f32x4 B1 = M1(af2, bfr[1][2], Z);
    f32x4 B2 = M1(af2, bfr[2][2], Z);
    f32x4 B3 = M1(af2, bfr[3][2], Z);

    // wave 0 only: pred for the OUTPUT (off the h critical path)
    f32x4 P0, P1;
    if (wv == 0){
      P0 = M1(af0, wfcfr[0], pbfcC);
      P1 = M1(af2, wfcfr[2], Z);
      P0 = M1(af1, wfcfr[1], P0);
      P1 = M1(af3, wfcfr[3], P1);
    }

    // stage 2
    A0 = M1(af1, bfr[0][1], A0);
    A1 = M1(af1, bfr[1][1], A1);
    A2 = M1(af1, bfr[2][1], A2);
    A3 = M1(af1, bfr[3][1], A3);
    B0 = M1(af3, bfr[0][3], B0);
    B1 = M1(af3, bfr[1][3], B1);
    B2 = M1(af3, bfr[2][3], B2);
    B3 = M1(af3, bfr[3][3], B3);

    float g0 = A0[0] + B0[0];
    float g1 = A1[0] + B1[0];
    float g2 = A2[0] + B2[0];
    float g3 = A3[0] + B3[0];
    float si = sigm(g0);
    float sf = sigm(g1);
    float tg = tnh(g2);
    float so = sigm(g3);
    cc = sf * cc + si * tg;
    h_lds[cur ^ 1][hwofs] = f2bf(so * tnh(cc));

    if (wv == 0 && n < 2)
      pred_lds[q][d * 2 + n] = f2bf(P0[0] + P1[0]);  // n&1==n for n<2

    __syncthreads();
    cur ^= 1;
  }

  // epilogue: pred_511 from final h (h_lds[cur])
  if (wv == 0){
    const ush* hb = &h_lds[cur][arow];
    bf16x8 af0 = *reinterpret_cast<const bf16x8*>(hb + 0 * 32 + q * 8);
    bf16x8 af1 = *reinterpret_cast<const bf16x8*>(hb + 1 * 32 + q * 8);
    bf16x8 af2 = *reinterpret_cast<const bf16x8*>(hb + 2 * 32 + q * 8);
    bf16x8 af3 = *reinterpret_cast<const bf16x8*>(hb + 3 * 32 + q * 8);
    f32x4 P0 = M1(af0, wfcfr[0], pbfcC);
    f32x4 P1 = M1(af2, wfcfr[2], Z);
    P0 = M1(af1, wfcfr[1], P0);
    P1 = M1(af3, wfcfr[3], P1);
    if (n < 2)
      pred_lds[q][(TDEC - 1) * 2 + n] = f2bf(P0[0] + P1[0]);
  }
  __syncthreads();

  // bulk coalesced output write: 4 rows x 1024 ush per block
  if (!isf32){
    int row = tid >> 7, c = (tid & 127) * 8;  // 512 threads x uint4
    uint4 v = *reinterpret_cast<const uint4*>(&pred_lds[row][c]);
    *reinterpret_cast<uint4*>((ush*)outg + (blk * RB + row) * (TDEC * 2) + c) = v;
  } else {
    for (int i = tid; i < RB * TDEC * 2; i += NTHR){
      int row = i >> 10, c = i & 1023;
      ((float*)outg)[(blk * RB + row) * (TDEC * 2) + c] = bf2f(pred_lds[row][c]);
    }
  }
}

extern "C" void kernel_launch(void* const* d_in, const int* in_sizes, int n_in,
                              void* d_out, int out_size, void* d_ws, size_t ws_size,
                              hipStream_t stream) {
  lstm_kernel<<<dim3(NBLK), dim3(NTHR), 0, stream>>>(
      d_in[0], d_in[1], d_in[2], d_in[3], d_in[4], d_in[5], d_in[6], d_out);
}

// Round 2
// 423.309 us; speedup vs baseline: 1.0207x; 1.0207x over previous
//
#include <hip/hip_runtime.h>

typedef unsigned short ush;
typedef unsigned int uint32;
typedef __attribute__((ext_vector_type(8))) __bf16 bf16x8;
typedef __attribute__((ext_vector_type(4))) float f32x4;

#define NBLK 256
#define RB   4     // batch rows per block
#define NTHR 512
#define SENC 256
#define TDEC 512
#define HDIM 128
#define HSTR 144   // h row stride (ush): 72 dw ≡ 8 mod 32 -> replicated reads/writes 2-way (free)
#define XSTR 520   // x row stride (ush)
#define PSTR 1024  // pred row stride (ush)

#define LOG2E  1.4426950408889634f
#define LOG2E2 2.8853900817779268f

__device__ __forceinline__ float bf2f(ush u){
  uint32 v = ((uint32)u) << 16;
  return __builtin_bit_cast(float, v);
}
__device__ __forceinline__ ush f2bf(float f){            // RNE via v_cvt
  return __builtin_bit_cast(ush, (__bf16)f);
}
__device__ __forceinline__ float lo16f(uint32 w){ return __builtin_bit_cast(float, w << 16); }
__device__ __forceinline__ float hi16f(uint32 w){ return __builtin_bit_cast(float, w & 0xFFFF0000u); }

__device__ __forceinline__ float loadf(const void* p, int i, bool f32){
  return f32 ? ((const float*)p)[i] : bf2f(((const ush*)p)[i]);
}
// raw bf16 fragment load: bit-exact copy of harness weights for bf16 inputs
__device__ __forceinline__ bf16x8 load8bf(const void* p, int i, bool f32){
  bf16x8 r;
  if (!f32){
    uint4 u = *reinterpret_cast<const uint4*>((const ush*)p + i);
    r = __builtin_bit_cast(bf16x8, u);
  } else {
    const float* fp = (const float*)p + i;
    #pragma unroll
    for (int j = 0; j < 8; ++j) r[j] = (__bf16)fp[j];
  }
  return r;
}
__device__ __forceinline__ float sigm(float x){
  return __builtin_amdgcn_rcpf(1.0f + __builtin_amdgcn_exp2f(-x * LOG2E));
}
__device__ __forceinline__ float tnh(float x){
  return 1.0f - 2.0f * __builtin_amdgcn_rcpf(__builtin_amdgcn_exp2f(x * LOG2E2) + 1.0f);
}
__device__ __forceinline__ f32x4 M1(bf16x8 a, bf16x8 b, f32x4 c){
  return __builtin_amdgcn_mfma_f32_16x16x32_bf16(a, b, c, 0, 0, 0);
}

// 256 blocks x 4 batch rows, 8 waves/block; wave w owns hidden cols [16w,16w+16).
// A-ROW REPLICATION: A[m]=h[m>>2]; lane (n,q) reads acc[0]. Gate K=128 as TWO
// independent depth-2 chains. DECODER WEIGHT FOLDING: pred feedback folded into
// Whh'/bias' -> pure h-recurrence. PRED BALANCING: waves {0,3,5,6} each do ONE
// K-slice partial pred MFMA (+1 MFMA per SIMD under either wave->SIMD mapping,
// vs +4 on one SIMD before); wave 1 sums the previous step's partials from LDS
// off the critical path. Loops unrolled x2 with static double-buffer indices.
__global__ void __launch_bounds__(NTHR, 2)
lstm_kernel(const void* __restrict__ xg,  const void* __restrict__ wih,
            const void* __restrict__ whh, const void* __restrict__ bih,
            const void* __restrict__ bhh, const void* __restrict__ wfc,
            const void* __restrict__ bfc, void* __restrict__ outg)
{
  __shared__ __attribute__((aligned(16))) ush x_lds[RB * XSTR];      // [row][t*2+c]
  __shared__ __attribute__((aligned(16))) ush h_lds[2][RB * HSTR];   // [buf][row][j]
  __shared__ __attribute__((aligned(16))) ush pred_lds[RB][PSTR];    // [row][d*2+o]
  __shared__ __attribute__((aligned(16))) float ppart[2][RB][2][4];  // [buf][row][o][kk]

  const int tid   = threadIdx.x;
  const int lane  = tid & 63;
  const int wv    = tid >> 6;
  const int n     = lane & 15;   // MFMA col index within tile (= A-row m)
  const int q     = lane >> 4;   // quad; this lane's batch row
  const int q8    = q * 8;
  const int gbase = wv << 4;
  const int blk   = blockIdx.x;

  // runtime storage-dtype detection (bf16 vs f32) from w_hh bit patterns
  const uint32* wp = (const uint32*)whh;
  int cnt = 0;
  #pragma unroll
  for (int i = 0; i < 64; ++i){
    uint32 e = (wp[i] >> 7) & 0xFFu;
    cnt += (e >= 90u && e <= 140u) ? 1 : 0;
  }
  const bool isf32 = (cnt < 40);

  for (int i = tid; i < 2 * RB * HSTR; i += NTHR) h_lds[0][i] = 0;  // both bufs

  // stage this block's 4 encoder rows into LDS as bf16: [row][t*2+c]
  if (!isf32){
    if (tid < 256){
      int row = tid >> 6, c = (tid & 63) * 8;
      uint4 v = *reinterpret_cast<const uint4*>((const ush*)xg + (blk * RB + row) * (SENC * 2) + c);
      *reinterpret_cast<uint4*>(&x_lds[row * XSTR + c]) = v;
    }
  } else {
    for (int i = tid; i < RB * SENC * 2; i += NTHR){
      int row = i >> 9, c = i & 511;
      x_lds[row * XSTR + c] = f2bf(((const float*)xg)[(blk * RB + row) * (SENC * 2) + c]);
    }
  }

  // ---- loop-invariant preloads: weights RAW (bit-exact for bf16) ----
  float wih0v[4], wih1v[4];
  f32x4 biasC[4];    // broadcast bias, used as C operand of first MFMA (chain A)
  bf16x8 bfr[4][4];  // [gate p][kk]: B[k][g]=Whh[g][k], k=kk*32+q*8+j, g=p*128+gbase+n
  #pragma unroll
  for (int p = 0; p < 4; ++p){
    int g = p * 128 + gbase + n;
    float b = loadf(bih, g, isf32) + loadf(bhh, g, isf32);
    biasC[p][0] = b; biasC[p][1] = b; biasC[p][2] = b; biasC[p][3] = b;
    wih0v[p] = loadf(wih, g * 2 + 0, isf32);
    wih1v[p] = loadf(wih, g * 2 + 1, isf32);
    #pragma unroll
    for (int kk = 0; kk < 4; ++kk)
      bfr[p][kk] = load8bf(whh, g * HDIM + kk * 32 + q8, isf32);
  }
  // pred partial setup: waves {0,3,5,6} own K-slices {0,1,2,3}; wave 1 sums.
  const bool ispred = (wv == 0) || (wv == 3) || (wv == 5) || (wv == 6);
  const bool issum  = (wv == 1);
  const int  pkk    = (wv == 0) ? 0 : (wv == 3) ? 1 : (wv == 5) ? 2 : 3;
  const int  pofs   = pkk * 32 + q8;
  bf16x8 wpfr;   // B[k][n] = wfc[n&1][k], k = pkk*32+q*8+j (column-replicated)
  #pragma unroll
  for (int j = 0; j < 8; ++j)
    wpfr[j] = (__bf16)loadf(wfc, (n & 1) * HDIM + pkk * 32 + q8 + j, isf32);
  f32x4 predC;   // bias rides on the kk==0 partial (wave 0)
  {
    float pb = (wv == 0) ? loadf(bfc, n & 1, isf32) : 0.0f;
    predC[0] = pb; predC[1] = pb; predC[2] = pb; predC[3] = pb;
  }

  float cc = 0.0f;                   // c-state for (row q, col gbase+n)
  const int arow  = (n >> 2) * HSTR; // replicated A-row base: A[m]=h[m>>2]
  const int hwofs = q * HSTR + gbase + n;  // this lane's h-write offset
  const f32x4 Z = {0.0f, 0.0f, 0.0f, 0.0f};

  __syncthreads();

#define LOADAF(RBUF) \
    const ush* hb = &h_lds[RBUF][arow]; \
    bf16x8 af0 = *reinterpret_cast<const bf16x8*>(hb + q8); \
    bf16x8 af1 = *reinterpret_cast<const bf16x8*>(hb + 32 + q8); \
    bf16x8 af2 = *reinterpret_cast<const bf16x8*>(hb + 64 + q8); \
    bf16x8 af3 = *reinterpret_cast<const bf16x8*>(hb + 96 + q8);

#define GATEMM \
    f32x4 A0 = M1(af0, bfr[0][0], biasC[0]); \
    f32x4 A1 = M1(af0, bfr[1][0], biasC[1]); \
    f32x4 A2 = M1(af0, bfr[2][0], biasC[2]); \
    f32x4 A3 = M1(af0, bfr[3][0], biasC[3]); \
    f32x4 B0 = M1(af2, bfr[0][2], Z); \
    f32x4 B1 = M1(af2, bfr[1][2], Z); \
    f32x4 B2 = M1(af2, bfr[2][2], Z); \
    f32x4 B3 = M1(af2, bfr[3][2], Z); \
    A0 = M1(af1, bfr[0][1], A0); \
    B0 = M1(af3, bfr[0][3], B0); \
    A1 = M1(af1, bfr[1][1], A1); \
    B1 = M1(af3, bfr[1][3], B1); \
    A2 = M1(af1, bfr[2][1], A2); \
    B2 = M1(af3, bfr[2][3], B2); \
    A3 = M1(af1, bfr[3][1], A3); \
    B3 = M1(af3, bfr[3][3], B3);

#define ENCSTEP(RBUF, WBUF, T) { \
    LOADAF(RBUF) \
    uint32 xw = *reinterpret_cast<const uint32*>(&x_lds[q * XSTR + (T) * 2]); \
    GATEMM \
    float xa = lo16f(xw), xb = hi16f(xw); \
    float g0 = A0[0] + B0[0] + (wih0v[0] * xa + wih1v[0] * xb); \
    float g1 = A1[0] + B1[0] + (wih0v[1] * xa + wih1v[1] * xb); \
    float g2 = A2[0] + B2[0] + (wih0v[2] * xa + wih1v[2] * xb); \
    float g3 = A3[0] + B3[0] + (wih0v[3] * xa + wih1v[3] * xb); \
    float si = sigm(g0); \
    float sf = sigm(g1); \
    float tg = tnh(g2); \
    float so = sigm(g3); \
    cc = sf * cc + si * tg; \
    h_lds[WBUF][hwofs] = f2bf(so * tnh(cc)); \
    __syncthreads(); \
  }

#define DECSTEP(RBUF, WBUF, D) { \
    LOADAF(RBUF) \
    if (issum && (D) > 0 && n < 2){ \
      f32x4 pp = *reinterpret_cast<const f32x4*>(&ppart[((D) - 1) & 1][q][n][0]); \
      pred_lds[q][((D) - 1) * 2 + n] = f2bf(pp[0] + pp[1] + pp[2] + pp[3]); \
    } \
    GATEMM \
    f32x4 PP = predC; \
    if (ispred) PP = M1(*reinterpret_cast<const bf16x8*>(hb + pofs), wpfr, predC); \
    float g0 = A0[0] + B0[0]; \
    float g1 = A1[0] + B1[0]; \
    float g2 = A2[0] + B2[0]; \
    float g3 = A3[0] + B3[0]; \
    float si = sigm(g0); \
    float sf = sigm(g1); \
    float tg = tnh(g2); \
    float so = sigm(g3); \
    cc = sf * cc + si * tg; \
    h_lds[WBUF][hwofs] = f2bf(so * tnh(cc)); \
    if (ispred && n < 2) ppart[(D) & 1][q][n][pkk] = PP[0]; \
    __syncthreads(); \
  }

  // ---------------- encoder: 256 steps + first decode cell ------------------
  #pragma unroll 1
  for (int s = 0; s < SENC; s += 2){
    ENCSTEP(0, 1, s)
    ENCSTEP(1, 0, s + 1)
  }
  ENCSTEP(0, 1, SENC - 1)   // s==SENC: inp0 = x[:,-1,:]; writes buf1

  // ---- decoder weight folding (once, in-register): ----
  //   Whh'[g][k] = Whh[g][k] + wih0[g]*wfc[0][k] + wih1[g]*wfc[1][k]
  //   bias'[g]   = bias[g]   + wih0[g]*bfc[0]    + wih1[g]*bfc[1]
  {
    float bfc0 = loadf(bfc, 0, isf32), bfc1 = loadf(bfc, 1, isf32);
    #pragma unroll
    for (int p = 0; p < 4; ++p){
      float nb = biasC[p][0] + wih0v[p] * bfc0 + wih1v[p] * bfc1;
      biasC[p][0] = nb; biasC[p][1] = nb; biasC[p][2] = nb; biasC[p][3] = nb;
    }
    #pragma unroll
    for (int kk = 0; kk < 4; ++kk){
      #pragma unroll
      for (int j = 0; j < 8; ++j){
        int k = kk * 32 + q8 + j;
        float w0 = loadf(wfc, k, isf32);          // wfc[0][k]
        float w1 = loadf(wfc, HDIM + k, isf32);   // wfc[1][k]
        #pragma unroll
        for (int p = 0; p < 4; ++p)
          bfr[p][kk][j] = (__bf16)((float)bfr[p][kk][j] + wih0v[p] * w0 + wih1v[p] * w1);
      }
    }
  }

  // ---------------- decoder: pure h-recurrence (folded weights) -------------
  #pragma unroll 1
  for (int d = 0; d < TDEC - 2; d += 2){
    DECSTEP(1, 0, d)
    DECSTEP(0, 1, d + 1)
  }
  DECSTEP(1, 0, TDEC - 2)   // d==510; final h lands in buf0

  // pending pred sum for d == TDEC-2 (buffer (TDEC-2)&1 == 0)
  if (issum && n < 2){
    f32x4 pp = *reinterpret_cast<const f32x4*>(&ppart[0][q][n][0]);
    pred_lds[q][(TDEC - 2) * 2 + n] = f2bf(pp[0] + pp[1] + pp[2] + pp[3]);
  }

  // epilogue: pred_511 from final h (buf0), wave 0 full chain
  if (wv == 0){
    LOADAF(0)
    bf16x8 wf0, wf1, wf2, wf3;
    #pragma unroll
    for (int j = 0; j < 8; ++j){
      wf0[j] = (__bf16)loadf(wfc, (n & 1) * HDIM +   0 + q8 + j, isf32);
      wf1[j] = (__bf16)loadf(wfc, (n & 1) * HDIM +  32 + q8 + j, isf32);
      wf2[j] = (__bf16)loadf(wfc, (n & 1) * HDIM +  64 + q8 + j, isf32);
      wf3[j] = (__bf16)loadf(wfc, (n & 1) * HDIM +  96 + q8 + j, isf32);
    }
    f32x4 P = M1(af0, wf0, predC);
    f32x4 Q = M1(af2, wf2, Z);
    P = M1(af1, wf1, P);
    Q = M1(af3, wf3, Q);
    if (n < 2)
      pred_lds[q][(TDEC - 1) * 2 + n] = f2bf(P[0] + Q[0]);
  }
  __syncthreads();

  // bulk coalesced output write: 4 rows x 1024 ush per block
  if (!isf32){
    int row = tid >> 7, c = (tid & 127) * 8;  // 512 threads x uint4
    uint4 v = *reinterpret_cast<const uint4*>(&pred_lds[row][c]);
    *reinterpret_cast<uint4*>((ush*)outg + (blk * RB + row) * (TDEC * 2) + c) = v;
  } else {
    for (int i = tid; i < RB * TDEC * 2; i += NTHR){
      int row = i >> 10, c = i & 1023;
      ((float*)outg)[(blk * RB + row) * (TDEC * 2) + c] = bf2f(pred_lds[row][c]);
    }
  }
}

extern "C" void kernel_launch(void* const* d_in, const int* in_sizes, int n_in,
                              void* d_out, int out_size, void* d_ws, size_t ws_size,
                              hipStream_t stream) {
  lstm_kernel<<<dim3(NBLK), dim3(NTHR), 0, stream>>>(
      d_in[0], d_in[1], d_in[2], d_in[3], d_in[4], d_in[5], d_in[6], d_out);
}

// Round 3
// 413.952 us; speedup vs baseline: 1.0438x; 1.0226x over previous
//
#include <hip/hip_runtime.h>

typedef unsigned short ush;
typedef unsigned int uint32;
typedef __attribute__((ext_vector_type(8))) __bf16 bf16x8;
typedef __attribute__((ext_vector_type(4))) float f32x4;

#define NBLK 256
#define RB   4     // batch rows per block
#define NTHR 512
#define SENC 256
#define TDEC 512
#define HDIM 128
#define HSTR 144   // h row stride (ush): 72 dw ≡ 8 mod 32 -> replicated reads/writes 2-way (free)
#define XSTR 520   // x row stride (ush)
#define PSTR 1024  // pred row stride (ush)

#define LOG2E  1.4426950408889634f
#define LOG2E2 2.8853900817779268f

__device__ __forceinline__ float bf2f(ush u){
  uint32 v = ((uint32)u) << 16;
  return __builtin_bit_cast(float, v);
}
__device__ __forceinline__ ush f2bf(float f){            // RNE via v_cvt
  return __builtin_bit_cast(ush, (__bf16)f);
}
__device__ __forceinline__ float lo16f(uint32 w){ return __builtin_bit_cast(float, w << 16); }
__device__ __forceinline__ float hi16f(uint32 w){ return __builtin_bit_cast(float, w & 0xFFFF0000u); }

__device__ __forceinline__ float loadf(const void* p, int i, bool f32){
  return f32 ? ((const float*)p)[i] : bf2f(((const ush*)p)[i]);
}
// raw bf16 fragment load: bit-exact copy of harness weights for bf16 inputs
__device__ __forceinline__ bf16x8 load8bf(const void* p, int i, bool f32){
  bf16x8 r;
  if (!f32){
    uint4 u = *reinterpret_cast<const uint4*>((const ush*)p + i);
    r = __builtin_bit_cast(bf16x8, u);
  } else {
    const float* fp = (const float*)p + i;
    #pragma unroll
    for (int j = 0; j < 8; ++j) r[j] = (__bf16)fp[j];
  }
  return r;
}
__device__ __forceinline__ f32x4 M1(bf16x8 a, bf16x8 b, f32x4 c){
  return __builtin_amdgcn_mfma_f32_16x16x32_bf16(a, b, c, 0, 0, 0);
}

// 256 blocks x 4 batch rows, 8 waves/block; wave w owns hidden cols [16w,16w+16).
// A-ROW REPLICATION: A[m]=h[m>>2]; lane (n,q) reads acc[0]. Gate K=128 as TWO
// independent depth-2 chains; g-gate (tanh, the longest post-chain) issued
// FIRST so its Eg chain starts earliest. DECODER WEIGHT FOLDING: pred feedback
// folded into Whh'/bias' -> pure h-recurrence. Pred partials balanced over
// waves {0,3,5,6}; wave 1 sums prev step's partials -- both placed AFTER the
// gate-MFMA issue so their LDS latency hides under the matrix crunch.
// TAIL with fused rcp: sigm(a)*tanh(b) = (Eb-1) * rcp((1+ea)(Eb+1)) -- 8 trans
// ops instead of 10. Encoder x-term rides the MFMA C-operand (slot 0 only;
// replica rows discarded). fmed3 clamps the tanh(cc) argument (identity:
// tanh saturates) to keep the (Ec-1)*rcp form overflow-safe.
__global__ void __launch_bounds__(NTHR, 2)
lstm_kernel(const void* __restrict__ xg,  const void* __restrict__ wih,
            const void* __restrict__ whh, const void* __restrict__ bih,
            const void* __restrict__ bhh, const void* __restrict__ wfc,
            const void* __restrict__ bfc, void* __restrict__ outg)
{
  __shared__ __attribute__((aligned(16))) ush x_lds[RB * XSTR];      // [row][t*2+c]
  __shared__ __attribute__((aligned(16))) ush h_lds[2][RB * HSTR];   // [buf][row][j]
  __shared__ __attribute__((aligned(16))) ush pred_lds[RB][PSTR];    // [row][d*2+o]
  __shared__ __attribute__((aligned(16))) float ppart[2][RB][2][4];  // [buf][row][o][kk]

  const int tid   = threadIdx.x;
  const int lane  = tid & 63;
  const int wv    = tid >> 6;
  const int n     = lane & 15;   // MFMA col index within tile (= A-row m)
  const int q     = lane >> 4;   // quad; this lane's batch row
  const int q8    = q * 8;
  const int gbase = wv << 4;
  const int blk   = blockIdx.x;

  // runtime storage-dtype detection (bf16 vs f32) from w_hh bit patterns
  const uint32* wp = (const uint32*)whh;
  int cnt = 0;
  #pragma unroll
  for (int i = 0; i < 64; ++i){
    uint32 e = (wp[i] >> 7) & 0xFFu;
    cnt += (e >= 90u && e <= 140u) ? 1 : 0;
  }
  const bool isf32 = (cnt < 40);

  for (int i = tid; i < 2 * RB * HSTR; i += NTHR) h_lds[0][i] = 0;  // both bufs

  // stage this block's 4 encoder rows into LDS as bf16: [row][t*2+c]
  if (!isf32){
    if (tid < 256){
      int row = tid >> 6, c = (tid & 63) * 8;
      uint4 v = *reinterpret_cast<const uint4*>((const ush*)xg + (blk * RB + row) * (SENC * 2) + c);
      *reinterpret_cast<uint4*>(&x_lds[row * XSTR + c]) = v;
    }
  } else {
    for (int i = tid; i < RB * SENC * 2; i += NTHR){
      int row = i >> 9, c = i & 511;
      x_lds[row * XSTR + c] = f2bf(((const float*)xg)[(blk * RB + row) * (SENC * 2) + c]);
    }
  }

  // ---- loop-invariant preloads: weights RAW (bit-exact for bf16) ----
  float wih0v[4], wih1v[4];
  f32x4 biasC[4];    // broadcast bias, used as C operand of first MFMA (chain A)
  bf16x8 bfr[4][4];  // [gate p][kk]: B[k][g]=Whh[g][k], k=kk*32+q*8+j, g=p*128+gbase+n
  #pragma unroll
  for (int p = 0; p < 4; ++p){
    int g = p * 128 + gbase + n;
    float b = loadf(bih, g, isf32) + loadf(bhh, g, isf32);
    biasC[p][0] = b; biasC[p][1] = b; biasC[p][2] = b; biasC[p][3] = b;
    wih0v[p] = loadf(wih, g * 2 + 0, isf32);
    wih1v[p] = loadf(wih, g * 2 + 1, isf32);
    #pragma unroll
    for (int kk = 0; kk < 4; ++kk)
      bfr[p][kk] = load8bf(whh, g * HDIM + kk * 32 + q8, isf32);
  }
  // pred partial setup: waves {0,3,5,6} own K-slices {0,1,2,3}; wave 1 sums.
  const bool ispred = (wv == 0) || (wv == 3) || (wv == 5) || (wv == 6);
  const bool issum  = (wv == 1);
  const int  pkk    = (wv == 0) ? 0 : (wv == 3) ? 1 : (wv == 5) ? 2 : 3;
  const int  pofs   = pkk * 32 + q8;
  bf16x8 wpfr;   // B[k][n] = wfc[n&1][k], k = pkk*32+q*8+j (column-replicated)
  #pragma unroll
  for (int j = 0; j < 8; ++j)
    wpfr[j] = (__bf16)loadf(wfc, (n & 1) * HDIM + pkk * 32 + q8 + j, isf32);
  f32x4 predC;   // bias rides on the kk==0 partial (wave 0)
  {
    float pb = (wv == 0) ? loadf(bfc, n & 1, isf32) : 0.0f;
    predC[0] = pb; predC[1] = pb; predC[2] = pb; predC[3] = pb;
  }

  float cc = 0.0f;                   // c-state for (row q, col gbase+n)
  const int arow  = (n >> 2) * HSTR; // replicated A-row base: A[m]=h[m>>2]
  const int hwofs = q * HSTR + gbase + n;  // this lane's h-write offset
  const f32x4 Z = {0.0f, 0.0f, 0.0f, 0.0f};

  __syncthreads();

#define LOADAF(RBUF) \
    const ush* hb = &h_lds[RBUF][arow]; \
    bf16x8 af0 = *reinterpret_cast<const bf16x8*>(hb + q8); \
    bf16x8 af1 = *reinterpret_cast<const bf16x8*>(hb + 32 + q8); \
    bf16x8 af2 = *reinterpret_cast<const bf16x8*>(hb + 64 + q8); \
    bf16x8 af3 = *reinterpret_cast<const bf16x8*>(hb + 96 + q8);

// g-gate (index 2) first: its stage-2 retires earliest -> Eg chain starts early
#define GATEMM(C0_, C1_, C2_, C3_) \
    f32x4 A2 = M1(af0, bfr[2][0], C2_); \
    f32x4 B2 = M1(af2, bfr[2][2], Z); \
    f32x4 A0 = M1(af0, bfr[0][0], C0_); \
    f32x4 B0 = M1(af2, bfr[0][2], Z); \
    f32x4 A1 = M1(af0, bfr[1][0], C1_); \
    f32x4 B1 = M1(af2, bfr[1][2], Z); \
    f32x4 A3 = M1(af0, bfr[3][0], C3_); \
    f32x4 B3 = M1(af2, bfr[3][2], Z); \
    A2 = M1(af1, bfr[2][1], A2); \
    B2 = M1(af3, bfr[2][3], B2); \
    A0 = M1(af1, bfr[0][1], A0); \
    B0 = M1(af3, bfr[0][3], B0); \
    A1 = M1(af1, bfr[1][1], A1); \
    B1 = M1(af3, bfr[1][3], B1); \
    A3 = M1(af1, bfr[3][1], A3); \
    B3 = M1(af3, bfr[3][3], B3);

// fused-rcp tail: sigm(a)*tanh(b) = (Eb-1)*rcp((1+ea)(Eb+1)); 8 trans ops
#define TAIL(WBUF) \
    float g2 = A2[0] + B2[0]; \
    float Eg = __builtin_amdgcn_exp2f(g2 * LOG2E2); \
    float g0 = A0[0] + B0[0]; \
    float ei = __builtin_amdgcn_exp2f(-g0 * LOG2E); \
    float g1 = A1[0] + B1[0]; \
    float ef = __builtin_amdgcn_exp2f(-g1 * LOG2E); \
    float g3 = A3[0] + B3[0]; \
    float eo = __builtin_amdgcn_exp2f(-g3 * LOG2E); \
    float sitg = (Eg - 1.0f) * __builtin_amdgcn_rcpf((1.0f + ei) * (Eg + 1.0f)); \
    float sf = __builtin_amdgcn_rcpf(1.0f + ef); \
    cc = sf * cc + sitg; \
    float ccl = __builtin_amdgcn_fmed3f(cc, -20.0f, 20.0f); \
    float Ec = __builtin_amdgcn_exp2f(ccl * LOG2E2); \
    float hh = (Ec - 1.0f) * __builtin_amdgcn_rcpf((1.0f + eo) * (Ec + 1.0f)); \
    h_lds[WBUF][hwofs] = f2bf(hh);

#define ENCSTEP(RBUF, WBUF, T) { \
    LOADAF(RBUF) \
    uint32 xw = *reinterpret_cast<const uint32*>(&x_lds[q * XSTR + (T) * 2]); \
    float xa = lo16f(xw), xb = hi16f(xw); \
    f32x4 C0 = biasC[0]; C0[0] = __builtin_fmaf(wih0v[0], xa, __builtin_fmaf(wih1v[0], xb, C0[0])); \
    f32x4 C1 = biasC[1]; C1[0] = __builtin_fmaf(wih0v[1], xa, __builtin_fmaf(wih1v[1], xb, C1[0])); \
    f32x4 C2 = biasC[2]; C2[0] = __builtin_fmaf(wih0v[2], xa, __builtin_fmaf(wih1v[2], xb, C2[0])); \
    f32x4 C3 = biasC[3]; C3[0] = __builtin_fmaf(wih0v[3], xa, __builtin_fmaf(wih1v[3], xb, C3[0])); \
    GATEMM(C0, C1, C2, C3) \
    TAIL(WBUF) \
    __syncthreads(); \
  }

#define DECSTEP(RBUF, WBUF, D) { \
    LOADAF(RBUF) \
    bf16x8 pfrag; \
    if (ispred) pfrag = *reinterpret_cast<const bf16x8*>(hb + pofs); \
    GATEMM(biasC[0], biasC[1], biasC[2], biasC[3]) \
    f32x4 PP; \
    if (ispred) PP = M1(pfrag, wpfr, predC); \
    if (issum && (D) > 0 && n < 2){ \
      f32x4 pp = *reinterpret_cast<const f32x4*>(&ppart[((D) - 1) & 1][q][n][0]); \
      pred_lds[q][((D) - 1) * 2 + n] = f2bf(pp[0] + pp[1] + pp[2] + pp[3]); \
    } \
    TAIL(WBUF) \
    if (ispred && n < 2) ppart[(D) & 1][q][n][pkk] = PP[0]; \
    __syncthreads(); \
  }

  // ---------------- encoder: 256 steps + first decode cell ------------------
  #pragma unroll 1
  for (int s = 0; s < SENC; s += 2){
    ENCSTEP(0, 1, s)
    ENCSTEP(1, 0, s + 1)
  }
  ENCSTEP(0, 1, SENC - 1)   // s==SENC: inp0 = x[:,-1,:]; writes buf1

  // ---- decoder weight folding (once, in-register): ----
  //   Whh'[g][k] = Whh[g][k] + wih0[g]*wfc[0][k] + wih1[g]*wfc[1][k]
  //   bias'[g]   = bias[g]   + wih0[g]*bfc[0]    + wih1[g]*bfc[1]
  {
    float bfc0 = loadf(bfc, 0, isf32), bfc1 = loadf(bfc, 1, isf32);
    #pragma unroll
    for (int p = 0; p < 4; ++p){
      float nb = biasC[p][0] + wih0v[p] * bfc0 + wih1v[p] * bfc1;
      biasC[p][0] = nb; biasC[p][1] = nb; biasC[p][2] = nb; biasC[p][3] = nb;
    }
    #pragma unroll
    for (int kk = 0; kk < 4; ++kk){
      #pragma unroll
      for (int j = 0; j < 8; ++j){
        int k = kk * 32 + q8 + j;
        float w0 = loadf(wfc, k, isf32);          // wfc[0][k]
        float w1 = loadf(wfc, HDIM + k, isf32);   // wfc[1][k]
        #pragma unroll
        for (int p = 0; p < 4; ++p)
          bfr[p][kk][j] = (__bf16)((float)bfr[p][kk][j] + wih0v[p] * w0 + wih1v[p] * w1);
      }
    }
  }

  // ---------------- decoder: pure h-recurrence (folded weights) -------------
  #pragma unroll 1
  for (int d = 0; d < TDEC - 2; d += 2){
    DECSTEP(1, 0, d)
    DECSTEP(0, 1, d + 1)
  }
  DECSTEP(1, 0, TDEC - 2)   // d==510; final h lands in buf0

  // pending pred sum for d == TDEC-2 (buffer (TDEC-2)&1 == 0)
  if (issum && n < 2){
    f32x4 pp = *reinterpret_cast<const f32x4*>(&ppart[0][q][n][0]);
    pred_lds[q][(TDEC - 2) * 2 + n] = f2bf(pp[0] + pp[1] + pp[2] + pp[3]);
  }

  // epilogue: pred_511 from final h (buf0), wave 0 full chain
  if (wv == 0){
    LOADAF(0)
    bf16x8 wf0, wf1, wf2, wf3;
    #pragma unroll
    for (int j = 0; j < 8; ++j){
      wf0[j] = (__bf16)loadf(wfc, (n & 1) * HDIM +   0 + q8 + j, isf32);
      wf1[j] = (__bf16)loadf(wfc, (n & 1) * HDIM +  32 + q8 + j, isf32);
      wf2[j] = (__bf16)loadf(wfc, (n & 1) * HDIM +  64 + q8 + j, isf32);
      wf3[j] = (__bf16)loadf(wfc, (n & 1) * HDIM +  96 + q8 + j, isf32);
    }
    f32x4 P = M1(af0, wf0, predC);
    f32x4 Q = M1(af2, wf2, Z);
    P = M1(af1, wf1, P);
    Q = M1(af3, wf3, Q);
    if (n < 2)
      pred_lds[q][(TDEC - 1) * 2 + n] = f2bf(P[0] + Q[0]);
  }
  __syncthreads();

  // bulk coalesced output write: 4 rows x 1024 ush per block
  if (!isf32){
    int row = tid >> 7, c = (tid & 127) * 8;  // 512 threads x uint4
    uint4 v = *reinterpret_cast<const uint4*>(&pred_lds[row][c]);
    *reinterpret_cast<uint4*>((ush*)outg + (blk * RB + row) * (TDEC * 2) + c) = v;
  } else {
    for (int i = tid; i < RB * TDEC * 2; i += NTHR){
      int row = i >> 10, c = i & 1023;
      ((float*)outg)[(blk * RB + row) * (TDEC * 2) + c] = bf2f(pred_lds[row][c]);
    }
  }
}

extern "C" void kernel_launch(void* const* d_in, const int* in_sizes, int n_in,
                              void* d_out, int out_size, void* d_ws, size_t ws_size,
                              hipStream_t stream) {
  lstm_kernel<<<dim3(NBLK), dim3(NTHR), 0, stream>>>(
      d_in[0], d_in[1], d_in[2], d_in[3], d_in[4], d_in[5], d_in[6], d_out);
}

// Round 5
// 406.976 us; speedup vs baseline: 1.0617x; 1.0171x over previous
//
#include <hip/hip_runtime.h>

typedef unsigned short ush;
typedef unsigned int uint32;
typedef __attribute__((ext_vector_type(8))) __bf16 bf16x8;
typedef __attribute__((ext_vector_type(4))) float f32x4;

#define NBLK 256
#define RB   4     // batch rows per block
#define NTHR 512
#define SENC 256
#define TDEC 512
#define HDIM 128
#define HSTR 144   // h row stride (ush): 72 dw ≡ 8 mod 32 -> replicated reads/writes 2-way (free)
#define XSTR 520   // x row stride (ush)
#define PSTR 1024  // pred row stride (ush)

#define LOG2E  1.4426950408889634f
#define LOG2E2 2.8853900817779268f

__device__ __forceinline__ float bf2f(ush u){
  uint32 v = ((uint32)u) << 16;
  return __builtin_bit_cast(float, v);
}
__device__ __forceinline__ ush f2bf(float f){            // RNE via v_cvt
  return __builtin_bit_cast(ush, (__bf16)f);
}
__device__ __forceinline__ float lo16f(uint32 w){ return __builtin_bit_cast(float, w << 16); }
__device__ __forceinline__ float hi16f(uint32 w){ return __builtin_bit_cast(float, w & 0xFFFF0000u); }

__device__ __forceinline__ float loadf(const void* p, int i, bool f32){
  return f32 ? ((const float*)p)[i] : bf2f(((const ush*)p)[i]);
}
// raw bf16 fragment load: bit-exact copy of harness weights for bf16 inputs
__device__ __forceinline__ bf16x8 load8bf(const void* p, int i, bool f32){
  bf16x8 r;
  if (!f32){
    uint4 u = *reinterpret_cast<const uint4*>((const ush*)p + i);
    r = __builtin_bit_cast(bf16x8, u);
  } else {
    const float* fp = (const float*)p + i;
    #pragma unroll
    for (int j = 0; j < 8; ++j) r[j] = (__bf16)fp[j];
  }
  return r;
}
__device__ __forceinline__ f32x4 M1(bf16x8 a, bf16x8 b, f32x4 c){
  return __builtin_amdgcn_mfma_f32_16x16x32_bf16(a, b, c, 0, 0, 0);
}

// 256 blocks x 4 batch rows, 8 waves/block; wave w owns hidden cols [16w,16w+16).
// A-ROW REPLICATION: A[m]=h[m>>2]; lane (n,q) reads acc[0]. Gate K=128 as TWO
// independent depth-2 chains; g-gate (deepest post-chain) issued FIRST, o-gate
// (shallowest) LAST. ds_reads ordered af0,af2 first (first MFMAs' operands).
// DECODER WEIGHT FOLDING: pred feedback folded into Whh'/bias' -> pure
// h-recurrence. Pred partials balanced over waves {0,3,5,6}; wave 1 sums prev
// step's partials (read issued pre-queue, write post-issue -- latency hidden).
// Encoder x-term: xc FMAs computed in MFMA-queue shadow, added post-MFMA
// (C-operand stays biasC: nothing between barrier-exit and first MFMA issue).
// TAIL fused rcp: sigm(a)*tanh(b) = (Eb-1)*rcp((1+ea)(Eb+1)); 8 trans ops.
// fmed3 clamps tanh(cc) arg (identity: tanh saturates) for overflow safety.
__global__ void __launch_bounds__(NTHR, 2)
lstm_kernel(const void* __restrict__ xg,  const void* __restrict__ wih,
            const void* __restrict__ whh, const void* __restrict__ bih,
            const void* __restrict__ bhh, const void* __restrict__ wfc,
            const void* __restrict__ bfc, void* __restrict__ outg)
{
  __shared__ __attribute__((aligned(16))) ush x_lds[RB * XSTR];      // [row][t*2+c]
  __shared__ __attribute__((aligned(16))) ush h_lds[2][RB * HSTR];   // [buf][row][j]
  __shared__ __attribute__((aligned(16))) ush pred_lds[RB][PSTR];    // [row][d*2+o]
  __shared__ __attribute__((aligned(16))) float ppart[2][RB][2][4];  // [buf][row][o][kk]

  const int tid   = threadIdx.x;
  const int lane  = tid & 63;
  const int wv    = tid >> 6;
  const int n     = lane & 15;   // MFMA col index within tile (= A-row m)
  const int q     = lane >> 4;   // quad; this lane's batch row
  const int q8    = q * 8;
  const int gbase = wv << 4;
  const int blk   = blockIdx.x;

  // runtime storage-dtype detection (bf16 vs f32) from w_hh bit patterns
  const uint32* wp = (const uint32*)whh;
  int cnt = 0;
  #pragma unroll
  for (int i = 0; i < 64; ++i){
    uint32 e = (wp[i] >> 7) & 0xFFu;
    cnt += (e >= 90u && e <= 140u) ? 1 : 0;
  }
  const bool isf32 = (cnt < 40);

  for (int i = tid; i < 2 * RB * HSTR; i += NTHR) h_lds[0][i] = 0;  // both bufs

  // stage this block's 4 encoder rows into LDS as bf16: [row][t*2+c]
  if (!isf32){
    if (tid < 256){
      int row = tid >> 6, c = (tid & 63) * 8;
      uint4 v = *reinterpret_cast<const uint4*>((const ush*)xg + (blk * RB + row) * (SENC * 2) + c);
      *reinterpret_cast<uint4*>(&x_lds[row * XSTR + c]) = v;
    }
  } else {
    for (int i = tid; i < RB * SENC * 2; i += NTHR){
      int row = i >> 9, c = i & 511;
      x_lds[row * XSTR + c] = f2bf(((const float*)xg)[(blk * RB + row) * (SENC * 2) + c]);
    }
  }

  // ---- loop-invariant preloads: weights RAW (bit-exact for bf16) ----
  float wih0v[4], wih1v[4];
  f32x4 biasC[4];    // broadcast bias, used as C operand of first MFMA (chain A)
  bf16x8 bfr[4][4];  // [gate p][kk]: B[k][g]=Whh[g][k], k=kk*32+q*8+j, g=p*128+gbase+n
  #pragma unroll
  for (int p = 0; p < 4; ++p){
    int g = p * 128 + gbase + n;
    float b = loadf(bih, g, isf32) + loadf(bhh, g, isf32);
    biasC[p][0] = b; biasC[p][1] = b; biasC[p][2] = b; biasC[p][3] = b;
    wih0v[p] = loadf(wih, g * 2 + 0, isf32);
    wih1v[p] = loadf(wih, g * 2 + 1, isf32);
    #pragma unroll
    for (int kk = 0; kk < 4; ++kk)
      bfr[p][kk] = load8bf(whh, g * HDIM + kk * 32 + q8, isf32);
  }
  // pred partial setup: waves {0,3,5,6} own K-slices {0,1,2,3}; wave 1 sums.
  const bool ispred = (wv == 0) || (wv == 3) || (wv == 5) || (wv == 6);
  const bool issum  = (wv == 1);
  const int  pkk    = (wv == 0) ? 0 : (wv == 3) ? 1 : (wv == 5) ? 2 : 3;
  const int  pofs   = pkk * 32 + q8;
  bf16x8 wpfr;   // B[k][n] = wfc[n&1][k], k = pkk*32+q*8+j (column-replicated)
  #pragma unroll
  for (int j = 0; j < 8; ++j)
    wpfr[j] = (__bf16)loadf(wfc, (n & 1) * HDIM + pkk * 32 + q8 + j, isf32);
  f32x4 predC;   // bias rides on the kk==0 partial (wave 0)
  {
    float pb = (wv == 0) ? loadf(bfc, n & 1, isf32) : 0.0f;
    predC[0] = pb; predC[1] = pb; predC[2] = pb; predC[3] = pb;
  }

  float cc = 0.0f;                   // c-state for (row q, col gbase+n)
  const int arow  = (n >> 2) * HSTR; // replicated A-row base: A[m]=h[m>>2]
  const int hwofs = q * HSTR + gbase + n;  // this lane's h-write offset
  const f32x4 Z = {0.0f, 0.0f, 0.0f, 0.0f};

  __syncthreads();

// af0/af2 first: the first two MFMAs consume them
#define LOADAF(RBUF) \
    const ush* hb = &h_lds[RBUF][arow]; \
    bf16x8 af0 = *reinterpret_cast<const bf16x8*>(hb + q8); \
    bf16x8 af2 = *reinterpret_cast<const bf16x8*>(hb + 64 + q8); \
    bf16x8 af1 = *reinterpret_cast<const bf16x8*>(hb + 32 + q8); \
    bf16x8 af3 = *reinterpret_cast<const bf16x8*>(hb + 96 + q8);

// g-gate (index 2) first: its stage-2 retires earliest -> Eg chain starts early
#define GATEMM \
    f32x4 A2 = M1(af0, bfr[2][0], biasC[2]); \
    f32x4 B2 = M1(af2, bfr[2][2], Z); \
    f32x4 A0 = M1(af0, bfr[0][0], biasC[0]); \
    f32x4 B0 = M1(af2, bfr[0][2], Z); \
    f32x4 A1 = M1(af0, bfr[1][0], biasC[1]); \
    f32x4 B1 = M1(af2, bfr[1][2], Z); \
    f32x4 A3 = M1(af0, bfr[3][0], biasC[3]); \
    f32x4 B3 = M1(af2, bfr[3][2], Z); \
    A2 = M1(af1, bfr[2][1], A2); \
    B2 = M1(af3, bfr[2][3], B2); \
    A0 = M1(af1, bfr[0][1], A0); \
    B0 = M1(af3, bfr[0][3], B0); \
    A1 = M1(af1, bfr[1][1], A1); \
    B1 = M1(af3, bfr[1][3], B1); \
    A3 = M1(af1, bfr[3][1], A3); \
    B3 = M1(af3, bfr[3][3], B3);

// fused-rcp tail: sigm(a)*tanh(b) = (Eb-1)*rcp((1+ea)(Eb+1)); 8 trans ops.
// XC0..3: extra additive gate terms (encoder x-contribution).
#define TAILE(WBUF, XC0, XC1, XC2, XC3) \
    float g2 = A2[0] + B2[0] + XC2; \
    float Eg = __builtin_amdgcn_exp2f(g2 * LOG2E2); \
    float g0 = A0[0] + B0[0] + XC0; \
    float ei = __builtin_amdgcn_exp2f(-g0 * LOG2E); \
    float g1 = A1[0] + B1[0] + XC1; \
    float ef = __builtin_amdgcn_exp2f(-g1 * LOG2E); \
    float g3 = A3[0] + B3[0] + XC3; \
    float eo = __builtin_amdgcn_exp2f(-g3 * LOG2E); \
    float sitg = (Eg - 1.0f) * __builtin_amdgcn_rcpf((1.0f + ei) * (Eg + 1.0f)); \
    float sf = __builtin_amdgcn_rcpf(1.0f + ef); \
    cc = sf * cc + sitg; \
    float ccl = __builtin_amdgcn_fmed3f(cc, -20.0f, 20.0f); \
    float Ec = __builtin_amdgcn_exp2f(ccl * LOG2E2); \
    float hh = (Ec - 1.0f) * __builtin_amdgcn_rcpf((1.0f + eo) * (Ec + 1.0f)); \
    h_lds[WBUF][hwofs] = f2bf(hh);

#define TAILD(WBUF) \
    float g2 = A2[0] + B2[0]; \
    float Eg = __builtin_amdgcn_exp2f(g2 * LOG2E2); \
    float g0 = A0[0] + B0[0]; \
    float ei = __builtin_amdgcn_exp2f(-g0 * LOG2E); \
    float g1 = A1[0] + B1[0]; \
    float ef = __builtin_amdgcn_exp2f(-g1 * LOG2E); \
    float g3 = A3[0] + B3[0]; \
    float eo = __builtin_amdgcn_exp2f(-g3 * LOG2E); \
    float sitg = (Eg - 1.0f) * __builtin_amdgcn_rcpf((1.0f + ei) * (Eg + 1.0f)); \
    float sf = __builtin_amdgcn_rcpf(1.0f + ef); \
    cc = sf * cc + sitg; \
    float ccl = __builtin_amdgcn_fmed3f(cc, -20.0f, 20.0f); \
    float Ec = __builtin_amdgcn_exp2f(ccl * LOG2E2); \
    float hh = (Ec - 1.0f) * __builtin_amdgcn_rcpf((1.0f + eo) * (Ec + 1.0f)); \
    h_lds[WBUF][hwofs] = f2bf(hh);

#define ENCSTEP(RBUF, WBUF, T) { \
    LOADAF(RBUF) \
    uint32 xw = *reinterpret_cast<const uint32*>(&x_lds[q * XSTR + (T) * 2]); \
    GATEMM \
    /* x contribution: FMAs issue in the MFMA-queue shadow */ \
    float xa = lo16f(xw), xb = hi16f(xw); \
    float xc0 = __builtin_fmaf(wih0v[0], xa, wih1v[0] * xb); \
    float xc1 = __builtin_fmaf(wih0v[1], xa, wih1v[1] * xb); \
    float xc2 = __builtin_fmaf(wih0v[2], xa, wih1v[2] * xb); \
    float xc3 = __builtin_fmaf(wih0v[3], xa, wih1v[3] * xb); \
    TAILE(WBUF, xc0, xc1, xc2, xc3) \
    __syncthreads(); \
  }

#define DECSTEP(RBUF, WBUF, D) { \
    LOADAF(RBUF) \
    bf16x8 pfrag; \
    if (ispred) pfrag = *reinterpret_cast<const bf16x8*>(hb + pofs); \
    f32x4 pp; \
    if (issum && (D) > 0 && n < 2) \
      pp = *reinterpret_cast<const f32x4*>(&ppart[((D) - 1) & 1][q][n][0]); \
    GATEMM \
    f32x4 PP; \
    if (ispred) PP = M1(pfrag, wpfr, predC); \
    if (issum && (D) > 0 && n < 2) \
      pred_lds[q][((D) - 1) * 2 + n] = f2bf(pp[0] + pp[1] + pp[2] + pp[3]); \
    if (ispred && n < 2) ppart[(D) & 1][q][n][pkk] = PP[0]; \
    TAILD(WBUF) \
    __syncthreads(); \
  }

  // ---------------- encoder: 256 steps + first decode cell ------------------
  #pragma unroll 1
  for (int s = 0; s < SENC; s += 2){
    ENCSTEP(0, 1, s)
    ENCSTEP(1, 0, s + 1)
  }
  ENCSTEP(0, 1, SENC - 1)   // s==SENC: inp0 = x[:,-1,:]; writes buf1

  // ---- decoder weight folding (once, in-register): ----
  //   Whh'[g][k] = Whh[g][k] + wih0[g]*wfc[0][k] + wih1[g]*wfc[1][k]
  //   bias'[g]   = bias[g]   + wih0[g]*bfc[0]    + wih1[g]*bfc[1]
  {
    float bfc0 = loadf(bfc, 0, isf32), bfc1 = loadf(bfc, 1, isf32);
    #pragma unroll
    for (int p = 0; p < 4; ++p){
      float nb = biasC[p][0] + wih0v[p] * bfc0 + wih1v[p] * bfc1;
      biasC[p][0] = nb; biasC[p][1] = nb; biasC[p][2] = nb; biasC[p][3] = nb;
    }
    #pragma unroll
    for (int kk = 0; kk < 4; ++kk){
      #pragma unroll
      for (int j = 0; j < 8; ++j){
        int k = kk * 32 + q8 + j;
        float w0 = loadf(wfc, k, isf32);          // wfc[0][k]
        float w1 = loadf(wfc, HDIM + k, isf32);   // wfc[1][k]
        #pragma unroll
        for (int p = 0; p < 4; ++p)
          bfr[p][kk][j] = (__bf16)((float)bfr[p][kk][j] + wih0v[p] * w0 + wih1v[p] * w1);
      }
    }
  }

  // ---------------- decoder: pure h-recurrence (folded weights) -------------
  #pragma unroll 1
  for (int d = 0; d < TDEC - 2; d += 2){
    DECSTEP(1, 0, d)
    DECSTEP(0, 1, d + 1)
  }
  DECSTEP(1, 0, TDEC - 2)   // d==510; final h lands in buf0

  // pending pred sum for d == TDEC-2 (buffer (TDEC-2)&1 == 0)
  if (issum && n < 2){
    f32x4 pp = *reinterpret_cast<const f32x4*>(&ppart[0][q][n][0]);
    pred_lds[q][(TDEC - 2) * 2 + n] = f2bf(pp[0] + pp[1] + pp[2] + pp[3]);
  }

  // epilogue: pred_511 from final h (buf0), wave 0 full chain
  if (wv == 0){
    LOADAF(0)
    bf16x8 wf0, wf1, wf2, wf3;
    #pragma unroll
    for (int j = 0; j < 8; ++j){
      wf0[j] = (__bf16)loadf(wfc, (n & 1) * HDIM +   0 + q8 + j, isf32);
      wf1[j] = (__bf16)loadf(wfc, (n & 1) * HDIM +  32 + q8 + j, isf32);
      wf2[j] = (__bf16)loadf(wfc, (n & 1) * HDIM +  64 + q8 + j, isf32);
      wf3[j] = (__bf16)loadf(wfc, (n & 1) * HDIM +  96 + q8 + j, isf32);
    }
    f32x4 P = M1(af0, wf0, predC);
    f32x4 Q = M1(af2, wf2, Z);
    P = M1(af1, wf1, P);
    Q = M1(af3, wf3, Q);
    if (n < 2)
      pred_lds[q][(TDEC - 1) * 2 + n] = f2bf(P[0] + Q[0]);
  }
  __syncthreads();

  // bulk coalesced output write: 4 rows x 1024 ush per block
  if (!isf32){
    int row = tid >> 7, c = (tid & 127) * 8;  // 512 threads x uint4
    uint4 v = *reinterpret_cast<const uint4*>(&pred_lds[row][c]);
    *reinterpret_cast<uint4*>((ush*)outg + (blk * RB + row) * (TDEC * 2) + c) = v;
  } else {
    for (int i = tid; i < RB * TDEC * 2; i += NTHR){
      int row = i >> 10, c = i & 1023;
      ((float*)outg)[(blk * RB + row) * (TDEC * 2) + c] = bf2f(pred_lds[row][c]);
    }
  }
}

extern "C" void kernel_launch(void* const* d_in, const int* in_sizes, int n_in,
                              void* d_out, int out_size, void* d_ws, size_t ws_size,
                              hipStream_t stream) {
  lstm_kernel<<<dim3(NBLK), dim3(NTHR), 0, stream>>>(
      d_in[0], d_in[1], d_in[2], d_in[3], d_in[4], d_in[5], d_in[6], d_out);
}